// Round 15
// baseline (1258.371 us; speedup 1.0000x reference)
//
#include <hip/hip_runtime.h>

// RATSQL relation-aware transformer layer, MI355X.
// Round 15: barrier-starved attention. R14 analysis: kernel is barrier/issue
// bound (20 barriers/block x 16 serial blocks/CU + 3000 inst/thread), not L2
// bound (PV already L1-served). Changes: shuffle-butterfly reductions (1
// barrier each), no Ek LDS staging (qek dots read L2 directly), no PV staging,
// float4 ps/vT, LDS 29.7->20.9 KB (7 blocks/CU). ~6 barriers/block.

typedef unsigned short bf16;

__global__ void cp_k(const float* __restrict__ in, float* __restrict__ out, int n) {
  int i = blockIdx.x * blockDim.x + threadIdx.x;
  int st = gridDim.x * blockDim.x;
  for (; i < n; i += st) out[i] = in[i];
}

// ---------- tiled GEMM: C = act(A(MxK) @ B(KxN) + bias), all fp32 ----------
__global__ __launch_bounds__(256) void gemm_k(
    const float* __restrict__ A, const float* __restrict__ Bw, size_t beoff,
    const float* __restrict__ bias, size_t boff, float* __restrict__ C,
    int M, int N, int K, int kvmode, int do_relu)
{
  __shared__ float As[16][68];
  __shared__ float Bs[16][68];
  int tid = threadIdx.x;
  int m0 = blockIdx.y * 64, n0 = blockIdx.x * 64;
  int tx = tid & 15, ty = tid >> 4;
  int arow = tid >> 2, acol = (tid & 3) << 2;
  int brow = tid >> 4, bcol = (tid & 15) << 2;
  float acc[4][4] = {{0.f}};
  for (int k0 = 0; k0 < K; k0 += 16) {
    float4 a4 = *(const float4*)(A + (size_t)(m0 + arow) * K + k0 + acol);
    As[acol + 0][arow] = a4.x;
    As[acol + 1][arow] = a4.y;
    As[acol + 2][arow] = a4.z;
    As[acol + 3][arow] = a4.w;
    float4 b4 = *(const float4*)(Bw + beoff + (size_t)(k0 + brow) * N + n0 + bcol);
    Bs[brow][bcol + 0] = b4.x;
    Bs[brow][bcol + 1] = b4.y;
    Bs[brow][bcol + 2] = b4.z;
    Bs[brow][bcol + 3] = b4.w;
    __syncthreads();
#pragma unroll
    for (int kk = 0; kk < 16; ++kk) {
      float a[4], b[4];
#pragma unroll
      for (int r = 0; r < 4; ++r) a[r] = As[kk][ty * 4 + r];
#pragma unroll
      for (int c = 0; c < 4; ++c) b[c] = Bs[kk][tx * 4 + c];
#pragma unroll
      for (int r = 0; r < 4; ++r)
#pragma unroll
        for (int c = 0; c < 4; ++c)
          acc[r][c] += a[r] * b[c];
    }
    __syncthreads();
  }
  float bv[4] = {0.f, 0.f, 0.f, 0.f};
  if (bias) {
#pragma unroll
    for (int c = 0; c < 4; ++c) bv[c] = bias[boff + n0 + tx * 4 + c];
  }
#pragma unroll
  for (int r = 0; r < 4; ++r) {
    int m = m0 + ty * 4 + r;
#pragma unroll
    for (int c = 0; c < 4; ++c) {
      int n = n0 + tx * 4 + c;
      float v = acc[r][c] + bv[c];
      if (do_relu) v = fmaxf(v, 0.f);
      if (!kvmode) {
        C[(size_t)m * N + n] = v;
      } else {
        int b = m >> 10, i = m & 1023, h = n >> 5, d = n & 31;
        C[(size_t)((((b << 3) + h) << 5) + d) * 1024 + i] = v;
      }
    }
  }
}

// ---------- fused QKV projection ----------
__global__ __launch_bounds__(256) void gemm_qkv_k(
    const float* __restrict__ A, const float* __restrict__ Wq,
    const float* __restrict__ Wk, const float* __restrict__ Wv, size_t beoff,
    float* __restrict__ q, float* __restrict__ kT, float* __restrict__ vT)
{
  __shared__ float As[16][68];
  __shared__ float Bs[16][68];
  int tid = threadIdx.x;
  int nt = blockIdx.x;
  int sel = nt >> 2;
  const float* Bw = (sel == 0) ? Wq : (sel == 1) ? Wk : Wv;
  float* C = (sel == 0) ? q : (sel == 1) ? kT : vT;
  int kvmode = (sel > 0);
  int m0 = blockIdx.y * 64, n0 = (nt & 3) * 64;
  const int N = 256, K = 256;
  int tx = tid & 15, ty = tid >> 4;
  int arow = tid >> 2, acol = (tid & 3) << 2;
  int brow = tid >> 4, bcol = (tid & 15) << 2;
  float acc[4][4] = {{0.f}};
  for (int k0 = 0; k0 < K; k0 += 16) {
    float4 a4 = *(const float4*)(A + (size_t)(m0 + arow) * K + k0 + acol);
    As[acol + 0][arow] = a4.x;
    As[acol + 1][arow] = a4.y;
    As[acol + 2][arow] = a4.z;
    As[acol + 3][arow] = a4.w;
    float4 b4 = *(const float4*)(Bw + beoff + (size_t)(k0 + brow) * N + n0 + bcol);
    Bs[brow][bcol + 0] = b4.x;
    Bs[brow][bcol + 1] = b4.y;
    Bs[brow][bcol + 2] = b4.z;
    Bs[brow][bcol + 3] = b4.w;
    __syncthreads();
#pragma unroll
    for (int kk = 0; kk < 16; ++kk) {
      float a[4], b[4];
#pragma unroll
      for (int r = 0; r < 4; ++r) a[r] = As[kk][ty * 4 + r];
#pragma unroll
      for (int c = 0; c < 4; ++c) b[c] = Bs[kk][tx * 4 + c];
#pragma unroll
      for (int r = 0; r < 4; ++r)
#pragma unroll
        for (int c = 0; c < 4; ++c)
          acc[r][c] += a[r] * b[c];
    }
    __syncthreads();
  }
#pragma unroll
  for (int r = 0; r < 4; ++r) {
    int m = m0 + ty * 4 + r;
#pragma unroll
    for (int c = 0; c < 4; ++c) {
      int n = n0 + tx * 4 + c;
      float v = acc[r][c];
      if (!kvmode) {
        C[(size_t)m * N + n] = v;
      } else {
        int b = m >> 10, i = m & 1023, h = n >> 5, d = n & 31;
        C[(size_t)((((b << 3) + h) << 5) + d) * 1024 + i] = v;
      }
    }
  }
}

// ---------- attention v5: shuffle reductions, minimal barriers ----------
__global__ __launch_bounds__(256) void attn5_k(
    const float* __restrict__ q, const float* __restrict__ kT,
    const float* __restrict__ vT, const float* __restrict__ Ek,
    const float* __restrict__ Ev, const int* __restrict__ rel,
    const int* __restrict__ msk, float* __restrict__ out)
{
  __shared__ float ps[4096];       // p[4][1024]
  __shared__ float qs[128];        // [i][d], pre-scaled
  __shared__ float qek[4 * 101];
  __shared__ float wbin[4 * 101];
  __shared__ float red[64];        // [0:16) wave-max, [16:32) wave-sum
  __shared__ float ovec[128];

  int tid = threadIdx.x;
  int wv = tid >> 6, lane = tid & 63;
  int tile = blockIdx.x & 255;
  int h = (blockIdx.x >> 8) & 7;
  int b = blockIdx.x >> 11;
  int i0 = tile << 2;

  if (tid < 128) {
    int i = tid >> 5, d = tid & 31;
    qs[tid] = q[(((size_t)(b * 1024 + i0 + i) * 8 + h) << 5) + d] * 0.17677669529663687f;
  }
  for (int p = tid; p < 404; p += 256) wbin[p] = 0.f;
  __syncthreads();  // (1) qs visible

  // qek[i][r] = qs[i]·Ek[r], Ek from L2 (broadcast across blocks)
  for (int p = tid; p < 400; p += 256) {
    int i = p / 100, r = p - i * 100;
    const float* ep = Ek + (r << 5);
    float s = 0.f;
#pragma unroll
    for (int d4 = 0; d4 < 8; ++d4) {
      float4 e = *(const float4*)(ep + (d4 << 2));
      s += qs[i * 32 + (d4 << 2) + 0] * e.x;
      s += qs[i * 32 + (d4 << 2) + 1] * e.y;
      s += qs[i * 32 + (d4 << 2) + 2] * e.z;
      s += qs[i * 32 + (d4 << 2) + 3] * e.w;
    }
    qek[i * 101 + r] = s;
  }
  __syncthreads();  // (2) qek visible

  const float* kTb = kT + ((size_t)(b * 8 + h) << 15);  // [d][j]
  const float* vTb = vT + ((size_t)(b * 8 + h) << 15);

  // ---- scores: thread covers j = 4*tid..4*tid+3, all 4 i ----
  int j0 = tid << 2;
  float sc4[4][4];  // [jj][i]
#pragma unroll
  for (int jj = 0; jj < 4; ++jj)
#pragma unroll
    for (int i = 0; i < 4; ++i) sc4[jj][i] = 0.f;
#pragma unroll
  for (int d = 0; d < 32; ++d) {
    float4 kv = *(const float4*)(kTb + (d << 10) + j0);
#pragma unroll
    for (int i = 0; i < 4; ++i) {
      float qv = qs[i * 32 + d];
      sc4[0][i] += qv * kv.x;
      sc4[1][i] += qv * kv.y;
      sc4[2][i] += qv * kv.z;
      sc4[3][i] += qv * kv.w;
    }
  }
  int rl[4][4];  // [jj][i]
  float mx[4];
#pragma unroll
  for (int i = 0; i < 4; ++i) {
    size_t ro = ((size_t)(b * 1024 + i0 + i) << 10) + j0;
    int4 rv = *(const int4*)(rel + ro);
    int4 mv = *(const int4*)(msk + ro);
    rl[0][i] = rv.x; rl[1][i] = rv.y; rl[2][i] = rv.z; rl[3][i] = rv.w;
    float a0 = sc4[0][i] + qek[i * 101 + rv.x];
    float a1 = sc4[1][i] + qek[i * 101 + rv.y];
    float a2 = sc4[2][i] + qek[i * 101 + rv.z];
    float a3 = sc4[3][i] + qek[i * 101 + rv.w];
    if (mv.x) a0 = -1e20f;
    if (mv.y) a1 = -1e20f;
    if (mv.z) a2 = -1e20f;
    if (mv.w) a3 = -1e20f;
    sc4[0][i] = a0; sc4[1][i] = a1; sc4[2][i] = a2; sc4[3][i] = a3;
    mx[i] = fmaxf(fmaxf(a0, a1), fmaxf(a2, a3));
  }

  // ---- max: in-wave butterfly + 16-float LDS combine ----
#pragma unroll
  for (int i = 0; i < 4; ++i) {
    float m = mx[i];
#pragma unroll
    for (int off = 32; off > 0; off >>= 1) m = fmaxf(m, __shfl_xor(m, off, 64));
    if (lane == 0) red[wv * 4 + i] = m;
  }
  __syncthreads();  // (3)
  float gm[4];
#pragma unroll
  for (int i = 0; i < 4; ++i)
    gm[i] = fmaxf(fmaxf(red[i], red[4 + i]), fmaxf(red[8 + i], red[12 + i]));

  // ---- exp, ps store (float4), histogram, partial sums ----
  float ts[4];
#pragma unroll
  for (int i = 0; i < 4; ++i) {
    float4 pv;
    pv.x = __expf(sc4[0][i] - gm[i]);
    pv.y = __expf(sc4[1][i] - gm[i]);
    pv.z = __expf(sc4[2][i] - gm[i]);
    pv.w = __expf(sc4[3][i] - gm[i]);
    *(float4*)(ps + (i << 10) + j0) = pv;
    ts[i] = pv.x + pv.y + pv.z + pv.w;
    atomicAdd(&wbin[i * 101 + rl[0][i]], pv.x);
    atomicAdd(&wbin[i * 101 + rl[1][i]], pv.y);
    atomicAdd(&wbin[i * 101 + rl[2][i]], pv.z);
    atomicAdd(&wbin[i * 101 + rl[3][i]], pv.w);
  }
#pragma unroll
  for (int i = 0; i < 4; ++i) {
    float s = ts[i];
#pragma unroll
    for (int off = 32; off > 0; off >>= 1) s += __shfl_xor(s, off, 64);
    if (lane == 0) red[16 + wv * 4 + i] = s;
  }
  __syncthreads();  // (4) ps + wave sums visible

  // ---- PV: wave wv = i, float4 j, direct vT (L1-shared across waves) ----
  float oacc[32];
#pragma unroll
  for (int d = 0; d < 32; ++d) oacc[d] = 0.f;
  for (int s = 0; s < 4; ++s) {
    int j = (lane << 2) + (s << 8);
    float4 p = *(const float4*)(ps + (wv << 10) + j);
#pragma unroll
    for (int d = 0; d < 32; ++d) {
      float4 v = *(const float4*)(vTb + (d << 10) + j);
      oacc[d] += p.x * v.x + p.y * v.y + p.z * v.z + p.w * v.w;
    }
  }
#pragma unroll
  for (int d = 0; d < 32; ++d) {
    float v = oacc[d];
#pragma unroll
    for (int off = 32; off > 0; off >>= 1) v += __shfl_xor(v, off, 64);
    if (lane == d) ovec[wv * 32 + d] = v;
  }
  __syncthreads();  // (5) ovec + histogram complete

  // ---- Ev term + normalize + write ----
  if (tid < 128) {
    int i = tid >> 5, d = tid & 31;
    float ev = 0.f;
    for (int r = 0; r < 100; ++r)
      ev += wbin[i * 101 + r] * Ev[(r << 5) + d];
    float denom = red[16 + i] + red[20 + i] + red[24 + i] + red[28 + i];
    out[(((size_t)(b * 1024 + i0 + i) * 8 + h) << 5) + d] =
        (ovec[i * 32 + d] + ev) / denom;
  }
}

// ---------- residual + LayerNorm ----------
__global__ __launch_bounds__(256) void ln_k(
    const float* __restrict__ x, const float* __restrict__ o,
    const float* __restrict__ g, const float* __restrict__ bta, size_t eoff,
    float* __restrict__ xo, float* __restrict__ fout)
{
  __shared__ float red[256];
  int row = blockIdx.x, t = threadIdx.x;
  size_t idx = (size_t)row * 256 + t;
  float r = x[idx] + o[idx];
  red[t] = r;
  __syncthreads();
  for (int off = 128; off > 0; off >>= 1) {
    if (t < off) red[t] += red[t + off];
    __syncthreads();
  }
  float mean = red[0] * (1.f / 256.f);
  __syncthreads();
  float dv = r - mean;
  red[t] = dv * dv;
  __syncthreads();
  for (int off = 128; off > 0; off >>= 1) {
    if (t < off) red[t] += red[t + off];
    __syncthreads();
  }
  float var = red[0] * (1.f / 256.f);
  float val = dv * rsqrtf(var + 1e-5f) * g[eoff + t] + bta[eoff + t];
  xo[idx] = val;
  if (fout) fout[idx] = val;
}

extern "C" void kernel_launch(void* const* d_in, const int* in_sizes, int n_in,
                              void* d_out, int out_size, void* d_ws, size_t ws_size,
                              hipStream_t stream) {
  const float* inp  = (const float*)d_in[0];
  const float* Wq   = (const float*)d_in[1];
  const float* Wk   = (const float*)d_in[2];
  const float* Wv   = (const float*)d_in[3];
  const float* Wo   = (const float*)d_in[4];
  const float* bo   = (const float*)d_in[5];
  const float* W1   = (const float*)d_in[6];
  const float* b1   = (const float*)d_in[7];
  const float* W2   = (const float*)d_in[8];
  const float* b2   = (const float*)d_in[9];
  const float* ln1g = (const float*)d_in[10];
  const float* ln1b = (const float*)d_in[11];
  const float* ln2g = (const float*)d_in[12];
  const float* ln2b = (const float*)d_in[13];
  const float* Ek   = (const float*)d_in[14];
  const float* Ev   = (const float*)d_in[15];
  const int*   rel  = (const int*)d_in[16];
  const int*   msk  = (const int*)d_in[17];

  const size_t SZ = 524288;  // 2048*256
  float* x    = (float*)d_ws;
  float* q    = x + SZ;                 // region R: q,kT,vT,attn = 8 MB
  float* kT   = q + SZ;
  float* vT   = kT + SZ;
  float* attn = vT + SZ;
  float* tmp  = attn + SZ;              // 2 MB
  float* ffh  = q;                      // 8 MB alias over R (dead during FF)

  cp_k<<<512, 256, 0, stream>>>(inp, x, (int)SZ);

  dim3 blk(256);
  for (int l = 0; l < 2; ++l) {
    size_t o_w  = (size_t)l * 65536;
    size_t o_b  = (size_t)l * 256;
    size_t o_w1 = (size_t)l * 262144;
    size_t o_b1 = (size_t)l * 1024;

    gemm_qkv_k<<<dim3(12, 32), blk, 0, stream>>>(x, Wq, Wk, Wv, o_w, q, kT, vT);

    attn5_k<<<4096, blk, 0, stream>>>(q, kT, vT, Ek, Ev, rel, msk, attn);

    gemm_k<<<dim3(4, 32), blk, 0, stream>>>(attn, Wo, o_w, bo, o_b, tmp,
                                            2048, 256, 256, 0, 0);
    ln_k<<<2048, blk, 0, stream>>>(x, tmp, ln1g, ln1b, o_b, x, nullptr);

    gemm_k<<<dim3(16, 32), blk, 0, stream>>>(x, W1, o_w1, b1, o_b1, ffh,
                                             2048, 1024, 256, 0, 1);
    gemm_k<<<dim3(4, 32), blk, 0, stream>>>(ffh, W2, o_w1, b2, o_b, tmp,
                                            2048, 256, 1024, 0, 0);
    ln_k<<<2048, blk, 0, stream>>>(x, tmp, ln2g, ln2b, o_b, x,
                                   (l == 1) ? (float*)d_out : nullptr);
  }
}

// Round 16
// 652.281 us; speedup vs baseline: 1.9292x; 1.9292x over previous
//
#include <hip/hip_runtime.h>

// RATSQL relation-aware transformer layer, MI355X.
// Round 16: attn2 (R12, 218us, 56 VGPR) restored; GEMM stack -> bf16 MFMA
// (16x16x32, fp32 accum). Weights pre-transposed [N][K] bf16; A staged
// fp32->bf16 in LDS; ffh kept bf16. R13/R15 lesson: keep VGPR<=~70.

typedef unsigned short ushortt;
typedef __attribute__((ext_vector_type(8))) short short8;    // 8 bf16 (4 VGPR)
typedef __attribute__((ext_vector_type(4))) float f32x4;

__device__ __forceinline__ ushortt f2bf(float f) {
  union { float f; unsigned int u; } c; c.f = f;
  unsigned int r = c.u + 0x7fffu + ((c.u >> 16) & 1u);
  return (ushortt)(r >> 16);
}
__device__ __forceinline__ unsigned int pk2(float a, float b) {
  return (unsigned int)f2bf(a) | ((unsigned int)f2bf(b) << 16);
}

__global__ void cp_k(const float* __restrict__ in, float* __restrict__ out, int n) {
  int i = blockIdx.x * blockDim.x + threadIdx.x;
  int st = gridDim.x * blockDim.x;
  for (; i < n; i += st) out[i] = in[i];
}

// W [K][N] fp32 (+off) -> WT [N][K] bf16
__global__ void wcvt_k(const float* __restrict__ W, size_t off,
                       ushortt* __restrict__ out, int lgK, int lgN, int total) {
  int i = blockIdx.x * blockDim.x + threadIdx.x;
  int st = gridDim.x * blockDim.x;
  for (; i < total; i += st) {
    int k = i & ((1 << lgK) - 1), n = i >> lgK;
    out[i] = f2bf(W[off + ((size_t)k << lgN) + n]);
  }
}

// ---------- shared MFMA GEMM body: 64x64 tile, 4 waves, K-step 32 ----------
// A: fp32 (a_bf=0) or bf16 (a_bf=1), row-major MxK. BT: bf16 [N][K].
// Out: kvmode -> (B,NH,DH,L); cbf -> bf16; else fp32 C.
__device__ __forceinline__ void mgemm_body(
    const void* __restrict__ A, int a_bf, const ushortt* __restrict__ BT,
    const float* __restrict__ bias, size_t boff,
    float* __restrict__ C, ushortt* __restrict__ cbf,
    int m0, int n0, int N, int K, int relu, int kvmode)
{
  __shared__ ushortt As[64 * 40];  // stride 40 (80B, 16B-aligned rows)
  __shared__ ushortt Bs[64 * 40];
  int tid = threadIdx.x;
  int wv = tid >> 6, lane = tid & 63;
  int quad = lane >> 4, mr = lane & 15;
  int sm = tid >> 2, k8 = (tid & 3) << 3;   // staging: row tid>>2, 8 k's

  f32x4 acc[4] = {};
  for (int k0 = 0; k0 < K; k0 += 32) {
    // stage A tile 64m x 32k
    if (!a_bf) {
      const float* ap = (const float*)A + (size_t)(m0 + sm) * K + k0 + k8;
      float4 f0 = *(const float4*)ap;
      float4 f1 = *(const float4*)(ap + 4);
      uint4 u;
      u.x = pk2(f0.x, f0.y); u.y = pk2(f0.z, f0.w);
      u.z = pk2(f1.x, f1.y); u.w = pk2(f1.z, f1.w);
      *(uint4*)(&As[sm * 40 + k8]) = u;
    } else {
      *(uint4*)(&As[sm * 40 + k8]) =
          *(const uint4*)((const ushortt*)A + (size_t)(m0 + sm) * K + k0 + k8);
    }
    // stage B tile 64n x 32k from BT[N][K]
    *(uint4*)(&Bs[sm * 40 + k8]) =
        *(const uint4*)(BT + (size_t)(n0 + sm) * K + k0 + k8);
    __syncthreads();
    short8 af = *(const short8*)(&As[(wv * 16 + mr) * 40 + quad * 8]);
#pragma unroll
    for (int nt = 0; nt < 4; ++nt) {
      short8 bf = *(const short8*)(&Bs[(nt * 16 + mr) * 40 + quad * 8]);
      acc[nt] = __builtin_amdgcn_mfma_f32_16x16x32_bf16(af, bf, acc[nt], 0, 0, 0);
    }
    __syncthreads();
  }
  // epilogue: D row = wv*16 + quad*4 + r, col = nt*16 + mr
#pragma unroll
  for (int nt = 0; nt < 4; ++nt) {
#pragma unroll
    for (int r = 0; r < 4; ++r) {
      int m = m0 + wv * 16 + quad * 4 + r;
      int n = n0 + nt * 16 + mr;
      float v = acc[nt][r];
      if (bias) v += bias[boff + n];
      if (relu) v = fmaxf(v, 0.f);
      if (cbf) {
        cbf[(size_t)m * N + n] = f2bf(v);
      } else if (kvmode) {
        int b = m >> 10, i = m & 1023, h = n >> 5, d = n & 31;
        C[(size_t)((((b << 3) + h) << 5) + d) * 1024 + i] = v;
      } else {
        C[(size_t)m * N + n] = v;
      }
    }
  }
}

// generic MFMA GEMM
__global__ __launch_bounds__(256) void mgemm_k(
    const void* __restrict__ A, int a_bf, const ushortt* __restrict__ BT,
    const float* __restrict__ bias, size_t boff,
    float* __restrict__ C, ushortt* __restrict__ cbf,
    int N, int K, int relu)
{
  mgemm_body(A, a_bf, BT, bias, boff, C, cbf,
             blockIdx.y * 64, blockIdx.x * 64, N, K, relu, 0);
}

// fused QKV: bx>>2 selects weight/output; WT holds wq@0, wk@65536, wv@131072
__global__ __launch_bounds__(256) void mqkv_k(
    const float* __restrict__ x, const ushortt* __restrict__ WT,
    float* __restrict__ q, float* __restrict__ kT, float* __restrict__ vT)
{
  int sel = blockIdx.x >> 2;
  const ushortt* BT = WT + (size_t)sel * 65536;
  float* C = (sel == 0) ? q : (sel == 1) ? kT : vT;
  mgemm_body(x, 0, BT, nullptr, 0, C, nullptr,
             blockIdx.y * 64, (blockIdx.x & 3) * 64, 256, 256, 0, sel > 0);
}

// ---------- attention (R12's attn2_k verbatim: 218us, 56 VGPR) ----------
__global__ __launch_bounds__(256) void attn2_k(
    const float* __restrict__ q, const float* __restrict__ kT,
    const float* __restrict__ vT, const float* __restrict__ Ek,
    const float* __restrict__ Ev, const int* __restrict__ rel,
    const int* __restrict__ msk, float* __restrict__ out)
{
  __shared__ float uni[4096];
  __shared__ float qs[128];
  __shared__ float qek[4 * 101];
  __shared__ float wbin[4 * 101];
  __shared__ float red4[1024];
  __shared__ float ovec[128];

  int tid = threadIdx.x;
  int tile = blockIdx.x & 255;
  int h = (blockIdx.x >> 8) & 7;
  int b = blockIdx.x >> 11;
  int i0 = tile << 2;

  for (int idx = tid; idx < 3200; idx += 256) {
    int r = idx >> 5, d = idx & 31;
    uni[r * 33 + d] = Ek[idx];
  }
  if (tid < 128) {
    int i = tid >> 5, d = tid & 31;
    qs[tid] = q[(((size_t)(b * 1024 + i0 + i) * 8 + h) << 5) + d] * 0.17677669529663687f;
  }
  __syncthreads();

  for (int p = tid; p < 400; p += 256) {
    int i = p / 100, r = p - i * 100;
    float s = 0.f;
#pragma unroll
    for (int d = 0; d < 32; ++d) s += qs[i * 32 + d] * uni[r * 33 + d];
    qek[i * 101 + r] = s;
    wbin[i * 101 + r] = 0.f;
  }
  __syncthreads();

  const float* kTb = kT + ((size_t)(b * 8 + h) << 15);
  const float* vTb = vT + ((size_t)(b * 8 + h) << 15);

  float sc[4][4];
  int rl[4][4];
  float mx[4] = {-3.0e38f, -3.0e38f, -3.0e38f, -3.0e38f};
#pragma unroll
  for (int s = 0; s < 4; ++s) {
    int j = tid + (s << 8);
    float acc[4] = {0.f, 0.f, 0.f, 0.f};
#pragma unroll
    for (int d = 0; d < 32; ++d) {
      float kv = kTb[(d << 10) + j];
#pragma unroll
      for (int i = 0; i < 4; ++i) acc[i] += qs[i * 32 + d] * kv;
    }
#pragma unroll
    for (int i = 0; i < 4; ++i) {
      size_t ro = ((size_t)(b * 1024 + i0 + i) << 10) + j;
      int rv = rel[ro];
      rl[s][i] = rv;
      float a = acc[i] + qek[i * 101 + rv];
      if (msk[ro]) a = -1e20f;
      sc[s][i] = a;
      mx[i] = fmaxf(mx[i], a);
    }
  }

#pragma unroll
  for (int i = 0; i < 4; ++i) red4[i * 256 + tid] = mx[i];
  __syncthreads();
  for (int off = 128; off > 0; off >>= 1) {
    if (tid < off) {
#pragma unroll
      for (int i = 0; i < 4; ++i)
        red4[i * 256 + tid] = fmaxf(red4[i * 256 + tid], red4[i * 256 + tid + off]);
    }
    __syncthreads();
  }
  float gm[4];
#pragma unroll
  for (int i = 0; i < 4; ++i) gm[i] = red4[i * 256];
  __syncthreads();

  float ts[4] = {0.f, 0.f, 0.f, 0.f};
#pragma unroll
  for (int s = 0; s < 4; ++s) {
    int j = tid + (s << 8);
#pragma unroll
    for (int i = 0; i < 4; ++i) {
      float p = __expf(sc[s][i] - gm[i]);
      uni[i * 1024 + j] = p;
      ts[i] += p;
      atomicAdd(&wbin[i * 101 + rl[s][i]], p);
    }
  }
#pragma unroll
  for (int i = 0; i < 4; ++i) red4[i * 256 + tid] = ts[i];
  __syncthreads();
  for (int off = 128; off > 0; off >>= 1) {
    if (tid < off) {
#pragma unroll
      for (int i = 0; i < 4; ++i)
        red4[i * 256 + tid] += red4[i * 256 + tid + off];
    }
    __syncthreads();
  }

  int wv = tid >> 6, lane = tid & 63;
  float oacc[32];
#pragma unroll
  for (int d = 0; d < 32; ++d) oacc[d] = 0.f;
  for (int s = 0; s < 16; ++s) {
    int j = lane + (s << 6);
    float p = uni[(wv << 10) + j];
#pragma unroll
    for (int d = 0; d < 32; ++d)
      oacc[d] += p * vTb[(d << 10) + j];
  }
#pragma unroll
  for (int d = 0; d < 32; ++d) {
    float v = oacc[d];
#pragma unroll
    for (int off = 32; off > 0; off >>= 1) v += __shfl_xor(v, off, 64);
    if (lane == d) ovec[wv * 32 + d] = v;
  }
  __syncthreads();

  if (tid < 128) {
    int i = tid >> 5, d = tid & 31;
    float ev = 0.f;
    for (int r = 0; r < 100; ++r)
      ev += wbin[i * 101 + r] * Ev[(r << 5) + d];
    float ginv = 1.f / red4[i * 256];
    out[(((size_t)(b * 1024 + i0 + i) * 8 + h) << 5) + d] =
        (ovec[i * 32 + d] + ev) * ginv;
  }
}

// ---------- residual + LayerNorm ----------
__global__ __launch_bounds__(256) void ln_k(
    const float* __restrict__ x, const float* __restrict__ o,
    const float* __restrict__ g, const float* __restrict__ bta, size_t eoff,
    float* __restrict__ xo, float* __restrict__ fout)
{
  __shared__ float red[256];
  int row = blockIdx.x, t = threadIdx.x;
  size_t idx = (size_t)row * 256 + t;
  float r = x[idx] + o[idx];
  red[t] = r;
  __syncthreads();
  for (int off = 128; off > 0; off >>= 1) {
    if (t < off) red[t] += red[t + off];
    __syncthreads();
  }
  float mean = red[0] * (1.f / 256.f);
  __syncthreads();
  float dv = r - mean;
  red[t] = dv * dv;
  __syncthreads();
  for (int off = 128; off > 0; off >>= 1) {
    if (t < off) red[t] += red[t + off];
    __syncthreads();
  }
  float var = red[0] * (1.f / 256.f);
  float val = dv * rsqrtf(var + 1e-5f) * g[eoff + t] + bta[eoff + t];
  xo[idx] = val;
  if (fout) fout[idx] = val;
}

extern "C" void kernel_launch(void* const* d_in, const int* in_sizes, int n_in,
                              void* d_out, int out_size, void* d_ws, size_t ws_size,
                              hipStream_t stream) {
  const float* inp  = (const float*)d_in[0];
  const float* Wq   = (const float*)d_in[1];
  const float* Wk   = (const float*)d_in[2];
  const float* Wv   = (const float*)d_in[3];
  const float* Wo   = (const float*)d_in[4];
  const float* bo   = (const float*)d_in[5];
  const float* W1   = (const float*)d_in[6];
  const float* b1   = (const float*)d_in[7];
  const float* W2   = (const float*)d_in[8];
  const float* b2   = (const float*)d_in[9];
  const float* ln1g = (const float*)d_in[10];
  const float* ln1b = (const float*)d_in[11];
  const float* ln2g = (const float*)d_in[12];
  const float* ln2b = (const float*)d_in[13];
  const float* Ek   = (const float*)d_in[14];
  const float* Ev   = (const float*)d_in[15];
  const int*   rel  = (const int*)d_in[16];
  const int*   msk  = (const int*)d_in[17];

  const size_t SZ = 524288;  // 2048*256
  float* x    = (float*)d_ws;
  float* q    = x + SZ;
  float* kT   = q + SZ;
  float* vT   = kT + SZ;
  float* attn = vT + SZ;
  float* tmp  = attn + SZ;              // 12 MB so far
  ushortt* wbuf = (ushortt*)(tmp + SZ); // 786432 bf16 = 1.5 MB (13.5 MB total)
  ushortt* ffh  = (ushortt*)q;          // 2048x1024 bf16 = 4 MB over q+kT

  cp_k<<<512, 256, 0, stream>>>(inp, x, (int)SZ);

  dim3 blk(256);
  for (int l = 0; l < 2; ++l) {
    size_t o_w  = (size_t)l * 65536;
    size_t o_b  = (size_t)l * 256;
    size_t o_w1 = (size_t)l * 262144;
    size_t o_b1 = (size_t)l * 1024;

    // per-layer weight transpose+convert: [N][K] bf16
    wcvt_k<<<64, 256, 0, stream>>>(Wq, o_w, wbuf + 0,      8, 8, 65536);
    wcvt_k<<<64, 256, 0, stream>>>(Wk, o_w, wbuf + 65536,  8, 8, 65536);
    wcvt_k<<<64, 256, 0, stream>>>(Wv, o_w, wbuf + 131072, 8, 8, 65536);
    wcvt_k<<<64, 256, 0, stream>>>(Wo, o_w, wbuf + 196608, 8, 8, 65536);
    wcvt_k<<<256, 256, 0, stream>>>(W1, o_w1, wbuf + 262144, 8, 10, 262144);
    wcvt_k<<<256, 256, 0, stream>>>(W2, o_w1, wbuf + 524288, 10, 8, 262144);

    mqkv_k<<<dim3(12, 32), blk, 0, stream>>>(x, wbuf, q, kT, vT);

    attn2_k<<<4096, blk, 0, stream>>>(q, kT, vT, Ek, Ev, rel, msk, attn);

    mgemm_k<<<dim3(4, 32), blk, 0, stream>>>(attn, 0, wbuf + 196608,
                                             bo, o_b, tmp, nullptr, 256, 256, 0);
    ln_k<<<2048, blk, 0, stream>>>(x, tmp, ln1g, ln1b, o_b, x, nullptr);

    mgemm_k<<<dim3(16, 32), blk, 0, stream>>>(x, 0, wbuf + 262144,
                                              b1, o_b1, nullptr, ffh, 1024, 256, 1);
    mgemm_k<<<dim3(4, 32), blk, 0, stream>>>(ffh, 1, wbuf + 524288,
                                             b2, o_b, tmp, nullptr, 256, 1024, 0);
    ln_k<<<2048, blk, 0, stream>>>(x, tmp, ln2g, ln2b, o_b, x,
                                   (l == 1) ? (float*)d_out : nullptr);
  }
}

// Round 17
// 467.003 us; speedup vs baseline: 2.6946x; 1.3967x over previous
//
#include <hip/hip_runtime.h>

// RATSQL relation-aware transformer layer, MI355X.
// Round 17: MFMA attention. Block=(b,h,16 i), QK^T and PV as 16x16x32 bf16
// MFMA; kT/v emitted bf16 by QKV epilogue in [d][j] / [j][d] layouts; softmax
// without max-subtraction (scores bounded, masked p=0 exactly); p LDS bf16
// stride-1028; qek/histogram trick retained. LDS 48KB -> 3 blocks/CU.

typedef unsigned short ushortt;
typedef __attribute__((ext_vector_type(8))) short short8;
typedef __attribute__((ext_vector_type(4))) float f32x4;

__device__ __forceinline__ ushortt f2bf(float f) {
  union { float f; unsigned int u; } c; c.f = f;
  unsigned int r = c.u + 0x7fffu + ((c.u >> 16) & 1u);
  return (ushortt)(r >> 16);
}
__device__ __forceinline__ unsigned int pk2(float a, float b) {
  return (unsigned int)f2bf(a) | ((unsigned int)f2bf(b) << 16);
}

__global__ void cp_k(const float* __restrict__ in, float* __restrict__ out, int n) {
  int i = blockIdx.x * blockDim.x + threadIdx.x;
  int st = gridDim.x * blockDim.x;
  for (; i < n; i += st) out[i] = in[i];
}

// W [K][N] fp32 (+off) -> WT [N][K] bf16
__global__ void wcvt_k(const float* __restrict__ W, size_t off,
                       ushortt* __restrict__ out, int lgK, int lgN, int total) {
  int i = blockIdx.x * blockDim.x + threadIdx.x;
  int st = gridDim.x * blockDim.x;
  for (; i < total; i += st) {
    int k = i & ((1 << lgK) - 1), n = i >> lgK;
    out[i] = f2bf(W[off + ((size_t)k << lgN) + n]);
  }
}

// ---------- MFMA GEMM body: 64x64 tile, 4 waves, K-step 32 ----------
// kvmode 0: C fp32 (or cbf bf16 row-major). 1: kT bf16 [d][j]. 2: v bf16 [j][d].
__device__ __forceinline__ void mgemm_body(
    const void* __restrict__ A, int a_bf, const ushortt* __restrict__ BT,
    const float* __restrict__ bias, size_t boff,
    float* __restrict__ C, ushortt* __restrict__ cbf,
    int m0, int n0, int N, int K, int relu, int kvmode)
{
  __shared__ ushortt As[64 * 40];
  __shared__ ushortt Bs[64 * 40];
  int tid = threadIdx.x;
  int wv = tid >> 6, lane = tid & 63;
  int quad = lane >> 4, mr = lane & 15;
  int sm = tid >> 2, k8 = (tid & 3) << 3;

  f32x4 acc[4] = {};
  for (int k0 = 0; k0 < K; k0 += 32) {
    if (!a_bf) {
      const float* ap = (const float*)A + (size_t)(m0 + sm) * K + k0 + k8;
      float4 f0 = *(const float4*)ap;
      float4 f1 = *(const float4*)(ap + 4);
      uint4 u;
      u.x = pk2(f0.x, f0.y); u.y = pk2(f0.z, f0.w);
      u.z = pk2(f1.x, f1.y); u.w = pk2(f1.z, f1.w);
      *(uint4*)(&As[sm * 40 + k8]) = u;
    } else {
      *(uint4*)(&As[sm * 40 + k8]) =
          *(const uint4*)((const ushortt*)A + (size_t)(m0 + sm) * K + k0 + k8);
    }
    *(uint4*)(&Bs[sm * 40 + k8]) =
        *(const uint4*)(BT + (size_t)(n0 + sm) * K + k0 + k8);
    __syncthreads();
    short8 af = *(const short8*)(&As[(wv * 16 + mr) * 40 + quad * 8]);
#pragma unroll
    for (int nt = 0; nt < 4; ++nt) {
      short8 bf = *(const short8*)(&Bs[(nt * 16 + mr) * 40 + quad * 8]);
      acc[nt] = __builtin_amdgcn_mfma_f32_16x16x32_bf16(af, bf, acc[nt], 0, 0, 0);
    }
    __syncthreads();
  }
#pragma unroll
  for (int nt = 0; nt < 4; ++nt) {
#pragma unroll
    for (int r = 0; r < 4; ++r) {
      int m = m0 + wv * 16 + quad * 4 + r;
      int n = n0 + nt * 16 + mr;
      float v = acc[nt][r];
      if (bias) v += bias[boff + n];
      if (relu) v = fmaxf(v, 0.f);
      if (kvmode == 1) {
        int b = m >> 10, i = m & 1023, h = n >> 5, d = n & 31;
        cbf[(size_t)(((b << 3) + h) * 32 + d) * 1024 + i] = f2bf(v);
      } else if (kvmode == 2) {
        int b = m >> 10, i = m & 1023, h = n >> 5, d = n & 31;
        cbf[(size_t)(((b << 3) + h) * 1024 + i) * 32 + d] = f2bf(v);
      } else if (cbf) {
        cbf[(size_t)m * N + n] = f2bf(v);
      } else {
        C[(size_t)m * N + n] = v;
      }
    }
  }
}

__global__ __launch_bounds__(256) void mgemm_k(
    const void* __restrict__ A, int a_bf, const ushortt* __restrict__ BT,
    const float* __restrict__ bias, size_t boff,
    float* __restrict__ C, ushortt* __restrict__ cbf,
    int N, int K, int relu)
{
  mgemm_body(A, a_bf, BT, bias, boff, C, cbf,
             blockIdx.y * 64, blockIdx.x * 64, N, K, relu, 0);
}

// fused QKV: sel 0 -> q fp32, 1 -> kT bf16 [d][j], 2 -> v bf16 [j][d]
__global__ __launch_bounds__(256) void mqkv_k(
    const float* __restrict__ x, const ushortt* __restrict__ WT,
    float* __restrict__ q, ushortt* __restrict__ kTbf, ushortt* __restrict__ vbf)
{
  int sel = blockIdx.x >> 2;
  const ushortt* BT = WT + (size_t)sel * 65536;
  mgemm_body(x, 0, BT, nullptr, 0,
             (sel == 0) ? q : nullptr,
             (sel == 1) ? kTbf : (sel == 2) ? vbf : nullptr,
             blockIdx.y * 64, (blockIdx.x & 3) * 64, 256, 256, 0, sel);
}

// ---------- MFMA attention: block = (b, h, 16 i's) ----------
__global__ __launch_bounds__(256) void attn_mf_k(
    const float* __restrict__ q, const ushortt* __restrict__ kTbf,
    const ushortt* __restrict__ vbf, const float* __restrict__ Ek,
    const float* __restrict__ Ev, const int* __restrict__ rel,
    const int* __restrict__ msk, float* __restrict__ out)
{
  __shared__ ushortt pbf[16 * 1028];   // p bf16, stride 1028 (2-way-free banks)
  __shared__ float regA[2144];         // qs(528)+qek(1616); later pvpart(2048)
  __shared__ float wbin[16 * 101];
  __shared__ float denom4[64];

  int tid = threadIdx.x;
  int wv = tid >> 6, lane = tid & 63;
  int quad = lane >> 4, mr = lane & 15;
  int tile = blockIdx.x & 63;
  int h = (blockIdx.x >> 6) & 7;
  int b = blockIdx.x >> 9;
  int i0 = tile << 4;

  float* qs = regA;            // [16][33]
  float* qek = regA + 528;     // [16][101]

  for (int idx = tid; idx < 512; idx += 256) {
    int i = idx >> 5, d = idx & 31;
    qs[i * 33 + d] = q[(((size_t)(b * 1024 + i0 + i) * 8 + h) << 5) + d]
                     * 0.17677669529663687f;
  }
  for (int p = tid; p < 1616; p += 256) wbin[p] = 0.f;  // covers 16*101
  __syncthreads();

  for (int p = tid; p < 1600; p += 256) {
    int i = p / 100, r = p - i * 100;
    const float* ep = Ek + (r << 5);
    float s = 0.f;
#pragma unroll
    for (int d = 0; d < 32; ++d) s += qs[i * 33 + d] * ep[d];
    qek[i * 101 + r] = s;
  }
  __syncthreads();

  // A-frag (q): A[m=mr][k=quad*8+jj]
  short8 qf;
#pragma unroll
  for (int jj = 0; jj < 8; ++jj)
    ((ushortt*)&qf)[jj] = f2bf(qs[mr * 33 + quad * 8 + jj]);

  const ushortt* kTs = kTbf + ((size_t)(b * 8 + h) << 15);  // [d][j]
  const ushortt* vs  = vbf + ((size_t)(b * 8 + h) << 15);   // [j][d]

  // ---- scores: wave wv covers n-tiles wv*16 .. wv*16+15 ----
  float psum[4] = {0.f, 0.f, 0.f, 0.f};
  for (int t = 0; t < 16; ++t) {
    int j0 = (wv * 16 + t) << 4;
    short8 kf;
#pragma unroll
    for (int jj = 0; jj < 8; ++jj)
      ((ushortt*)&kf)[jj] = kTs[((quad * 8 + jj) << 10) + j0 + mr];
    f32x4 z = {};
    f32x4 s = __builtin_amdgcn_mfma_f32_16x16x32_bf16(qf, kf, z, 0, 0, 0);
#pragma unroll
    for (int r = 0; r < 4; ++r) {
      int i = quad * 4 + r;
      int j = j0 + mr;
      size_t ro = ((size_t)(b * 1024 + i0 + i) << 10) + j;
      int rv = rel[ro];
      float p = 0.f;
      if (!msk[ro]) {
        p = __expf(s[r] + qek[i * 101 + rv]);
        atomicAdd(&wbin[i * 101 + rv], p);
      }
      psum[r] += p;
      pbf[i * 1028 + j] = f2bf(p);
    }
  }
  // denominator partials: reduce over mr lanes (bits 0..3)
#pragma unroll
  for (int r = 0; r < 4; ++r) {
    float s = psum[r];
    s += __shfl_xor(s, 1, 64);
    s += __shfl_xor(s, 2, 64);
    s += __shfl_xor(s, 4, 64);
    s += __shfl_xor(s, 8, 64);
    if (mr == 0) denom4[wv * 16 + quad * 4 + r] = s;
  }
  __syncthreads();  // p, wbin, denom4 complete; regA free

  // ---- PV: ntile = wv&1 (d0), khalf = wv>>1 (k0) ----
  float* pvpart = regA;  // [2][1024]
  int d0 = (wv & 1) << 4;
  int k0 = (wv >> 1) << 9;
  f32x4 acc = {};
  for (int kt = 0; kt < 16; ++kt) {
    int kk = k0 + (kt << 5);
    short8 pf = *(const short8*)(&pbf[mr * 1028 + kk + quad * 8]);
    short8 vf;
#pragma unroll
    for (int jj = 0; jj < 8; ++jj)
      ((ushortt*)&vf)[jj] = vs[((kk + quad * 8 + jj) << 5) + d0 + mr];
    acc = __builtin_amdgcn_mfma_f32_16x16x32_bf16(pf, vf, acc, 0, 0, 0);
  }
  if (wv >= 2) {
#pragma unroll
    for (int r = 0; r < 4; ++r)
      pvpart[((wv & 1) << 10) + (lane << 2) + r] = acc[r];
  }
  __syncthreads();

  // ---- epilogue: waves 0,1 hold final tiles ----
  if (wv < 2) {
#pragma unroll
    for (int r = 0; r < 4; ++r) {
      int i = quad * 4 + r;
      int d = d0 + mr;
      float pv = acc[r] + pvpart[(wv << 10) + (lane << 2) + r];
      float ev = 0.f;
      for (int rr = 0; rr < 100; ++rr)
        ev += wbin[i * 101 + rr] * Ev[(rr << 5) + d];
      float den = denom4[i] + denom4[16 + i] + denom4[32 + i] + denom4[48 + i];
      out[(((size_t)(b * 1024 + i0 + i) * 8 + h) << 5) + d] = (pv + ev) / den;
    }
  }
}

// ---------- residual + LayerNorm ----------
__global__ __launch_bounds__(256) void ln_k(
    const float* __restrict__ x, const float* __restrict__ o,
    const float* __restrict__ g, const float* __restrict__ bta, size_t eoff,
    float* __restrict__ xo, float* __restrict__ fout)
{
  __shared__ float red[256];
  int row = blockIdx.x, t = threadIdx.x;
  size_t idx = (size_t)row * 256 + t;
  float r = x[idx] + o[idx];
  red[t] = r;
  __syncthreads();
  for (int off = 128; off > 0; off >>= 1) {
    if (t < off) red[t] += red[t + off];
    __syncthreads();
  }
  float mean = red[0] * (1.f / 256.f);
  __syncthreads();
  float dv = r - mean;
  red[t] = dv * dv;
  __syncthreads();
  for (int off = 128; off > 0; off >>= 1) {
    if (t < off) red[t] += red[t + off];
    __syncthreads();
  }
  float var = red[0] * (1.f / 256.f);
  float val = dv * rsqrtf(var + 1e-5f) * g[eoff + t] + bta[eoff + t];
  xo[idx] = val;
  if (fout) fout[idx] = val;
}

extern "C" void kernel_launch(void* const* d_in, const int* in_sizes, int n_in,
                              void* d_out, int out_size, void* d_ws, size_t ws_size,
                              hipStream_t stream) {
  const float* inp  = (const float*)d_in[0];
  const float* Wq   = (const float*)d_in[1];
  const float* Wk   = (const float*)d_in[2];
  const float* Wv   = (const float*)d_in[3];
  const float* Wo   = (const float*)d_in[4];
  const float* bo   = (const float*)d_in[5];
  const float* W1   = (const float*)d_in[6];
  const float* b1   = (const float*)d_in[7];
  const float* W2   = (const float*)d_in[8];
  const float* b2   = (const float*)d_in[9];
  const float* ln1g = (const float*)d_in[10];
  const float* ln1b = (const float*)d_in[11];
  const float* ln2g = (const float*)d_in[12];
  const float* ln2b = (const float*)d_in[13];
  const float* Ek   = (const float*)d_in[14];
  const float* Ev   = (const float*)d_in[15];
  const int*   rel  = (const int*)d_in[16];
  const int*   msk  = (const int*)d_in[17];

  const size_t SZ = 524288;  // 2048*256
  float* x      = (float*)d_ws;              // 2 MB
  float* q      = x + SZ;                    // 2 MB fp32
  ushortt* kTbf = (ushortt*)(q + SZ);        // 1 MB bf16 [d][j] per (b,h)
  ushortt* vbf  = kTbf + SZ;                 // 1 MB bf16 [j][d] per (b,h)
  float* attn   = (float*)(vbf + SZ);        // 2 MB
  float* tmp    = attn + SZ;                 // 2 MB
  ushortt* wbuf = (ushortt*)(tmp + SZ);      // 1.5 MB
  ushortt* ffh  = (ushortt*)q;               // 4 MB alias over q+kTbf+vbf

  cp_k<<<512, 256, 0, stream>>>(inp, x, (int)SZ);

  dim3 blk(256);
  for (int l = 0; l < 2; ++l) {
    size_t o_w  = (size_t)l * 65536;
    size_t o_b  = (size_t)l * 256;
    size_t o_w1 = (size_t)l * 262144;
    size_t o_b1 = (size_t)l * 1024;

    wcvt_k<<<64, 256, 0, stream>>>(Wq, o_w, wbuf + 0,      8, 8, 65536);
    wcvt_k<<<64, 256, 0, stream>>>(Wk, o_w, wbuf + 65536,  8, 8, 65536);
    wcvt_k<<<64, 256, 0, stream>>>(Wv, o_w, wbuf + 131072, 8, 8, 65536);
    wcvt_k<<<64, 256, 0, stream>>>(Wo, o_w, wbuf + 196608, 8, 8, 65536);
    wcvt_k<<<256, 256, 0, stream>>>(W1, o_w1, wbuf + 262144, 8, 10, 262144);
    wcvt_k<<<256, 256, 0, stream>>>(W2, o_w1, wbuf + 524288, 10, 8, 262144);

    mqkv_k<<<dim3(12, 32), blk, 0, stream>>>(x, wbuf, q, kTbf, vbf);

    attn_mf_k<<<1024, blk, 0, stream>>>(q, kTbf, vbf, Ek, Ev, rel, msk, attn);

    mgemm_k<<<dim3(4, 32), blk, 0, stream>>>(attn, 0, wbuf + 196608,
                                             bo, o_b, tmp, nullptr, 256, 256, 0);
    ln_k<<<2048, blk, 0, stream>>>(x, tmp, ln1g, ln1b, o_b, x, nullptr);

    mgemm_k<<<dim3(16, 32), blk, 0, stream>>>(x, 0, wbuf + 262144,
                                              b1, o_b1, nullptr, ffh, 1024, 256, 1);
    mgemm_k<<<dim3(4, 32), blk, 0, stream>>>(ffh, 1, wbuf + 524288,
                                             b2, o_b, tmp, nullptr, 256, 1024, 0);
    ln_k<<<2048, blk, 0, stream>>>(x, tmp, ln2g, ln2b, o_b, x,
                                   (l == 1) ? (float*)d_out : nullptr);
  }
}

// Round 18
// 451.980 us; speedup vs baseline: 2.7841x; 1.0332x over previous
//
#include <hip/hip_runtime.h>

// RATSQL relation-aware transformer layer, MI355X.
// Round 18: fix attention fragment layouts. QK^T B-frag wants [j][d]
// (8 consecutive d), PV B-frag wants [d][j] (8 consecutive j) — R17 had both
// swapped => 8x scalar gathers per fragment. QKV now emits k=[j][d], v=[d][j];
// attention loads short8 fragments as single 16B loads. cp_k dropped (layer 0
// reads inp directly).

typedef unsigned short ushortt;
typedef __attribute__((ext_vector_type(8))) short short8;
typedef __attribute__((ext_vector_type(4))) float f32x4;

__device__ __forceinline__ ushortt f2bf(float f) {
  union { float f; unsigned int u; } c; c.f = f;
  unsigned int r = c.u + 0x7fffu + ((c.u >> 16) & 1u);
  return (ushortt)(r >> 16);
}
__device__ __forceinline__ unsigned int pk2(float a, float b) {
  return (unsigned int)f2bf(a) | ((unsigned int)f2bf(b) << 16);
}

// W [K][N] fp32 (+off) -> WT [N][K] bf16
__global__ void wcvt_k(const float* __restrict__ W, size_t off,
                       ushortt* __restrict__ out, int lgK, int lgN, int total) {
  int i = blockIdx.x * blockDim.x + threadIdx.x;
  int st = gridDim.x * blockDim.x;
  for (; i < total; i += st) {
    int k = i & ((1 << lgK) - 1), n = i >> lgK;
    out[i] = f2bf(W[off + ((size_t)k << lgN) + n]);
  }
}

// ---------- MFMA GEMM body: 64x64 tile, 4 waves, K-step 32 ----------
// kvmode 0: C fp32 / cbf bf16 row-major. 1: bf16 [d][j] (v). 2: bf16 [j][d] (k).
__device__ __forceinline__ void mgemm_body(
    const void* __restrict__ A, int a_bf, const ushortt* __restrict__ BT,
    const float* __restrict__ bias, size_t boff,
    float* __restrict__ C, ushortt* __restrict__ cbf,
    int m0, int n0, int N, int K, int relu, int kvmode)
{
  __shared__ ushortt As[64 * 40];
  __shared__ ushortt Bs[64 * 40];
  int tid = threadIdx.x;
  int wv = tid >> 6, lane = tid & 63;
  int quad = lane >> 4, mr = lane & 15;
  int sm = tid >> 2, k8 = (tid & 3) << 3;

  f32x4 acc[4] = {};
  for (int k0 = 0; k0 < K; k0 += 32) {
    if (!a_bf) {
      const float* ap = (const float*)A + (size_t)(m0 + sm) * K + k0 + k8;
      float4 f0 = *(const float4*)ap;
      float4 f1 = *(const float4*)(ap + 4);
      uint4 u;
      u.x = pk2(f0.x, f0.y); u.y = pk2(f0.z, f0.w);
      u.z = pk2(f1.x, f1.y); u.w = pk2(f1.z, f1.w);
      *(uint4*)(&As[sm * 40 + k8]) = u;
    } else {
      *(uint4*)(&As[sm * 40 + k8]) =
          *(const uint4*)((const ushortt*)A + (size_t)(m0 + sm) * K + k0 + k8);
    }
    *(uint4*)(&Bs[sm * 40 + k8]) =
        *(const uint4*)(BT + (size_t)(n0 + sm) * K + k0 + k8);
    __syncthreads();
    short8 af = *(const short8*)(&As[(wv * 16 + mr) * 40 + quad * 8]);
#pragma unroll
    for (int nt = 0; nt < 4; ++nt) {
      short8 bf = *(const short8*)(&Bs[(nt * 16 + mr) * 40 + quad * 8]);
      acc[nt] = __builtin_amdgcn_mfma_f32_16x16x32_bf16(af, bf, acc[nt], 0, 0, 0);
    }
    __syncthreads();
  }
#pragma unroll
  for (int nt = 0; nt < 4; ++nt) {
#pragma unroll
    for (int r = 0; r < 4; ++r) {
      int m = m0 + wv * 16 + quad * 4 + r;
      int n = n0 + nt * 16 + mr;
      float v = acc[nt][r];
      if (bias) v += bias[boff + n];
      if (relu) v = fmaxf(v, 0.f);
      if (kvmode == 1) {
        int b = m >> 10, i = m & 1023, h = n >> 5, d = n & 31;
        cbf[(size_t)(((b << 3) + h) * 32 + d) * 1024 + i] = f2bf(v);
      } else if (kvmode == 2) {
        int b = m >> 10, i = m & 1023, h = n >> 5, d = n & 31;
        cbf[(size_t)(((b << 3) + h) * 1024 + i) * 32 + d] = f2bf(v);
      } else if (cbf) {
        cbf[(size_t)m * N + n] = f2bf(v);
      } else {
        C[(size_t)m * N + n] = v;
      }
    }
  }
}

__global__ __launch_bounds__(256) void mgemm_k(
    const void* __restrict__ A, int a_bf, const ushortt* __restrict__ BT,
    const float* __restrict__ bias, size_t boff,
    float* __restrict__ C, ushortt* __restrict__ cbf,
    int N, int K, int relu)
{
  mgemm_body(A, a_bf, BT, bias, boff, C, cbf,
             blockIdx.y * 64, blockIdx.x * 64, N, K, relu, 0);
}

// fused QKV: sel 0 -> q fp32; sel 1 (Wk) -> k bf16 [j][d]; sel 2 (Wv) -> v bf16 [d][j]
__global__ __launch_bounds__(256) void mqkv_k(
    const float* __restrict__ x, const ushortt* __restrict__ WT,
    float* __restrict__ q, ushortt* __restrict__ kbf, ushortt* __restrict__ vTbf)
{
  int sel = blockIdx.x >> 2;
  const ushortt* BT = WT + (size_t)sel * 65536;
  int mode = (sel == 1) ? 2 : (sel == 2) ? 1 : 0;
  mgemm_body(x, 0, BT, nullptr, 0,
             (sel == 0) ? q : nullptr,
             (sel == 1) ? kbf : (sel == 2) ? vTbf : nullptr,
             blockIdx.y * 64, (blockIdx.x & 3) * 64, 256, 256, 0, mode);
}

// ---------- MFMA attention: block = (b, h, 16 i's) ----------
__global__ __launch_bounds__(256) void attn_mf_k(
    const float* __restrict__ q, const ushortt* __restrict__ kbf,
    const ushortt* __restrict__ vTbf, const float* __restrict__ Ek,
    const float* __restrict__ Ev, const int* __restrict__ rel,
    const int* __restrict__ msk, float* __restrict__ out)
{
  __shared__ ushortt pbf[16 * 1028];
  __shared__ float regA[2144];         // qs(528)+qek(1616); later pvpart(2048)
  __shared__ float wbin[16 * 101];
  __shared__ float denom4[64];

  int tid = threadIdx.x;
  int wv = tid >> 6, lane = tid & 63;
  int quad = lane >> 4, mr = lane & 15;
  int tile = blockIdx.x & 63;
  int h = (blockIdx.x >> 6) & 7;
  int b = blockIdx.x >> 9;
  int i0 = tile << 4;

  float* qs = regA;            // [16][33]
  float* qek = regA + 528;     // [16][101]

  for (int idx = tid; idx < 512; idx += 256) {
    int i = idx >> 5, d = idx & 31;
    qs[i * 33 + d] = q[(((size_t)(b * 1024 + i0 + i) * 8 + h) << 5) + d]
                     * 0.17677669529663687f;
  }
  for (int p = tid; p < 1616; p += 256) wbin[p] = 0.f;
  __syncthreads();

  for (int p = tid; p < 1600; p += 256) {
    int i = p / 100, r = p - i * 100;
    const float* ep = Ek + (r << 5);
    float s = 0.f;
#pragma unroll
    for (int d = 0; d < 32; ++d) s += qs[i * 33 + d] * ep[d];
    qek[i * 101 + r] = s;
  }
  __syncthreads();

  // A-frag (q): A[m=mr][k=quad*8+jj]
  short8 qf;
#pragma unroll
  for (int jj = 0; jj < 8; ++jj)
    ((ushortt*)&qf)[jj] = f2bf(qs[mr * 33 + quad * 8 + jj]);

  const ushortt* ks = kbf + ((size_t)(b * 8 + h) << 15);   // [j][d]
  const ushortt* vs = vTbf + ((size_t)(b * 8 + h) << 15);  // [d][j]

  // ---- scores: wave wv covers n-tiles wv*16 .. wv*16+15 ----
  float psum[4] = {0.f, 0.f, 0.f, 0.f};
  for (int t = 0; t < 16; ++t) {
    int j0 = (wv * 16 + t) << 4;
    // B-frag: B[k=quad*8+jj][n=mr] = k_{j0+mr}[quad*8+jj] -> [j][d] contiguous
    short8 kf = *(const short8*)(ks + ((size_t)(j0 + mr) << 5) + quad * 8);
    f32x4 z = {};
    f32x4 s = __builtin_amdgcn_mfma_f32_16x16x32_bf16(qf, kf, z, 0, 0, 0);
#pragma unroll
    for (int r = 0; r < 4; ++r) {
      int i = quad * 4 + r;
      int j = j0 + mr;
      size_t ro = ((size_t)(b * 1024 + i0 + i) << 10) + j;
      int rv = rel[ro];
      float p = 0.f;
      if (!msk[ro]) {
        p = __expf(s[r] + qek[i * 101 + rv]);
        atomicAdd(&wbin[i * 101 + rv], p);
      }
      psum[r] += p;
      pbf[i * 1028 + j] = f2bf(p);
    }
  }
#pragma unroll
  for (int r = 0; r < 4; ++r) {
    float s = psum[r];
    s += __shfl_xor(s, 1, 64);
    s += __shfl_xor(s, 2, 64);
    s += __shfl_xor(s, 4, 64);
    s += __shfl_xor(s, 8, 64);
    if (mr == 0) denom4[wv * 16 + quad * 4 + r] = s;
  }
  __syncthreads();

  // ---- PV: ntile = wv&1 (d0), khalf = wv>>1 (k0) ----
  float* pvpart = regA;
  int d0 = (wv & 1) << 4;
  int k0 = (wv >> 1) << 9;
  f32x4 acc = {};
  for (int kt = 0; kt < 16; ++kt) {
    int kk = k0 + (kt << 5);
    short8 pf = *(const short8*)(&pbf[mr * 1028 + kk + quad * 8]);
    // B-frag: V[k=kk+quad*8+jj][n=d0+mr] -> [d][j] contiguous in j
    short8 vf = *(const short8*)(vs + ((size_t)(d0 + mr) << 10) + kk + quad * 8);
    acc = __builtin_amdgcn_mfma_f32_16x16x32_bf16(pf, vf, acc, 0, 0, 0);
  }
  if (wv >= 2) {
#pragma unroll
    for (int r = 0; r < 4; ++r)
      pvpart[((wv & 1) << 10) + (lane << 2) + r] = acc[r];
  }
  __syncthreads();

  if (wv < 2) {
#pragma unroll
    for (int r = 0; r < 4; ++r) {
      int i = quad * 4 + r;
      int d = d0 + mr;
      float pv = acc[r] + pvpart[(wv << 10) + (lane << 2) + r];
      float ev = 0.f;
      for (int rr = 0; rr < 100; ++rr)
        ev += wbin[i * 101 + rr] * Ev[(rr << 5) + d];
      float den = denom4[i] + denom4[16 + i] + denom4[32 + i] + denom4[48 + i];
      out[(((size_t)(b * 1024 + i0 + i) * 8 + h) << 5) + d] = (pv + ev) / den;
    }
  }
}

// ---------- residual + LayerNorm ----------
__global__ __launch_bounds__(256) void ln_k(
    const float* __restrict__ x, const float* __restrict__ o,
    const float* __restrict__ g, const float* __restrict__ bta, size_t eoff,
    float* __restrict__ xo, float* __restrict__ fout)
{
  __shared__ float red[256];
  int row = blockIdx.x, t = threadIdx.x;
  size_t idx = (size_t)row * 256 + t;
  float r = x[idx] + o[idx];
  red[t] = r;
  __syncthreads();
  for (int off = 128; off > 0; off >>= 1) {
    if (t < off) red[t] += red[t + off];
    __syncthreads();
  }
  float mean = red[0] * (1.f / 256.f);
  __syncthreads();
  float dv = r - mean;
  red[t] = dv * dv;
  __syncthreads();
  for (int off = 128; off > 0; off >>= 1) {
    if (t < off) red[t] += red[t + off];
    __syncthreads();
  }
  float var = red[0] * (1.f / 256.f);
  float val = dv * rsqrtf(var + 1e-5f) * g[eoff + t] + bta[eoff + t];
  xo[idx] = val;
  if (fout) fout[idx] = val;
}

extern "C" void kernel_launch(void* const* d_in, const int* in_sizes, int n_in,
                              void* d_out, int out_size, void* d_ws, size_t ws_size,
                              hipStream_t stream) {
  const float* inp  = (const float*)d_in[0];
  const float* Wq   = (const float*)d_in[1];
  const float* Wk   = (const float*)d_in[2];
  const float* Wv   = (const float*)d_in[3];
  const float* Wo   = (const float*)d_in[4];
  const float* bo   = (const float*)d_in[5];
  const float* W1   = (const float*)d_in[6];
  const float* b1   = (const float*)d_in[7];
  const float* W2   = (const float*)d_in[8];
  const float* b2   = (const float*)d_in[9];
  const float* ln1g = (const float*)d_in[10];
  const float* ln1b = (const float*)d_in[11];
  const float* ln2g = (const float*)d_in[12];
  const float* ln2b = (const float*)d_in[13];
  const float* Ek   = (const float*)d_in[14];
  const float* Ev   = (const float*)d_in[15];
  const int*   rel  = (const int*)d_in[16];
  const int*   msk  = (const int*)d_in[17];

  const size_t SZ = 524288;  // 2048*256
  float* x      = (float*)d_ws;              // 2 MB
  float* q      = x + SZ;                    // 2 MB fp32
  ushortt* kbf  = (ushortt*)(q + SZ);        // 1 MB bf16 [j][d] per (b,h)
  ushortt* vTbf = kbf + SZ;                  // 1 MB bf16 [d][j] per (b,h)
  float* attn   = (float*)(vTbf + SZ);       // 2 MB
  float* tmp    = attn + SZ;                 // 2 MB
  ushortt* wbuf = (ushortt*)(tmp + SZ);      // 1.5 MB
  ushortt* ffh  = (ushortt*)q;               // 4 MB alias over q+kbf+vTbf

  dim3 blk(256);
  for (int l = 0; l < 2; ++l) {
    size_t o_w  = (size_t)l * 65536;
    size_t o_b  = (size_t)l * 256;
    size_t o_w1 = (size_t)l * 262144;
    size_t o_b1 = (size_t)l * 1024;
    const float* xin = (l == 0) ? inp : x;

    wcvt_k<<<64, 256, 0, stream>>>(Wq, o_w, wbuf + 0,      8, 8, 65536);
    wcvt_k<<<64, 256, 0, stream>>>(Wk, o_w, wbuf + 65536,  8, 8, 65536);
    wcvt_k<<<64, 256, 0, stream>>>(Wv, o_w, wbuf + 131072, 8, 8, 65536);
    wcvt_k<<<64, 256, 0, stream>>>(Wo, o_w, wbuf + 196608, 8, 8, 65536);
    wcvt_k<<<256, 256, 0, stream>>>(W1, o_w1, wbuf + 262144, 8, 10, 262144);
    wcvt_k<<<256, 256, 0, stream>>>(W2, o_w1, wbuf + 524288, 10, 8, 262144);

    mqkv_k<<<dim3(12, 32), blk, 0, stream>>>(xin, wbuf, q, kbf, vTbf);

    attn_mf_k<<<1024, blk, 0, stream>>>(q, kbf, vTbf, Ek, Ev, rel, msk, attn);

    mgemm_k<<<dim3(4, 32), blk, 0, stream>>>(attn, 0, wbuf + 196608,
                                             bo, o_b, tmp, nullptr, 256, 256, 0);
    ln_k<<<2048, blk, 0, stream>>>(xin, tmp, ln1g, ln1b, o_b, x, nullptr);

    mgemm_k<<<dim3(16, 32), blk, 0, stream>>>(x, 0, wbuf + 262144,
                                              b1, o_b1, nullptr, ffh, 1024, 256, 1);
    mgemm_k<<<dim3(4, 32), blk, 0, stream>>>(ffh, 1, wbuf + 524288,
                                             b2, o_b, tmp, nullptr, 256, 1024, 0);
    ln_k<<<2048, blk, 0, stream>>>(x, tmp, ln2g, ln2b, o_b, x,
                                   (l == 1) ? (float*)d_out : nullptr);
  }
}

// Round 19
// 448.745 us; speedup vs baseline: 2.8042x; 1.0072x over previous
//
#include <hip/hip_runtime.h>

// RATSQL relation-aware transformer layer, MI355X.
// Round 19: occupancy-first attention. R18 NEUTRAL: frag layout wasn't the
// bottleneck; LDS 48.6KB -> 3 blocks/CU (occ 24%) is. Block now covers 8 i's:
// LDS ~24KB -> 6 blocks/CU, grid 2048. MFMA rows 8..15 are don't-care (rows
// independent). 12 wcvt launches fused into one up-front kernel (both layers).

typedef unsigned short ushortt;
typedef __attribute__((ext_vector_type(8))) short short8;
typedef __attribute__((ext_vector_type(4))) float f32x4;

__device__ __forceinline__ ushortt f2bf(float f) {
  union { float f; unsigned int u; } c; c.f = f;
  unsigned int r = c.u + 0x7fffu + ((c.u >> 16) & 1u);
  return (ushortt)(r >> 16);
}
__device__ __forceinline__ unsigned int pk2(float a, float b) {
  return (unsigned int)f2bf(a) | ((unsigned int)f2bf(b) << 16);
}

// one launch: both layers' six weights -> [N][K] bf16 in wbuf
__global__ void wcvt_all_k(const float* __restrict__ Wq, const float* __restrict__ Wk,
                           const float* __restrict__ Wv, const float* __restrict__ Wo,
                           const float* __restrict__ W1, const float* __restrict__ W2,
                           ushortt* __restrict__ wbuf) {
  int i = blockIdx.x * blockDim.x + threadIdx.x;
  int st = gridDim.x * blockDim.x;
  for (; i < 1572864; i += st) {
    int l = (i >= 786432) ? 1 : 0;
    int e = i - (l ? 786432 : 0);
    size_t o_w = (size_t)l * 65536, o_w1 = (size_t)l * 262144;
    float v;
    if (e < 262144) {
      int which = e >> 16;
      int loc = e & 65535;
      int k = loc & 255, n = loc >> 8;
      const float* W = (which == 0) ? Wq : (which == 1) ? Wk : (which == 2) ? Wv : Wo;
      v = W[o_w + ((size_t)k << 8) + n];
    } else if (e < 524288) {
      int loc = e - 262144;
      int k = loc & 255, n = loc >> 8;
      v = W1[o_w1 + ((size_t)k << 10) + n];
    } else {
      int loc = e - 524288;
      int k = loc & 1023, n = loc >> 10;
      v = W2[o_w1 + ((size_t)k << 8) + n];
    }
    wbuf[i] = f2bf(v);
  }
}

// ---------- MFMA GEMM body: 64x64 tile, 4 waves, K-step 32 ----------
// kvmode 0: C fp32 / cbf bf16 row-major. 1: bf16 [d][j] (v). 2: bf16 [j][d] (k).
__device__ __forceinline__ void mgemm_body(
    const void* __restrict__ A, int a_bf, const ushortt* __restrict__ BT,
    const float* __restrict__ bias, size_t boff,
    float* __restrict__ C, ushortt* __restrict__ cbf,
    int m0, int n0, int N, int K, int relu, int kvmode)
{
  __shared__ ushortt As[64 * 40];
  __shared__ ushortt Bs[64 * 40];
  int tid = threadIdx.x;
  int wv = tid >> 6, lane = tid & 63;
  int quad = lane >> 4, mr = lane & 15;
  int sm = tid >> 2, k8 = (tid & 3) << 3;

  f32x4 acc[4] = {};
  for (int k0 = 0; k0 < K; k0 += 32) {
    if (!a_bf) {
      const float* ap = (const float*)A + (size_t)(m0 + sm) * K + k0 + k8;
      float4 f0 = *(const float4*)ap;
      float4 f1 = *(const float4*)(ap + 4);
      uint4 u;
      u.x = pk2(f0.x, f0.y); u.y = pk2(f0.z, f0.w);
      u.z = pk2(f1.x, f1.y); u.w = pk2(f1.z, f1.w);
      *(uint4*)(&As[sm * 40 + k8]) = u;
    } else {
      *(uint4*)(&As[sm * 40 + k8]) =
          *(const uint4*)((const ushortt*)A + (size_t)(m0 + sm) * K + k0 + k8);
    }
    *(uint4*)(&Bs[sm * 40 + k8]) =
        *(const uint4*)(BT + (size_t)(n0 + sm) * K + k0 + k8);
    __syncthreads();
    short8 af = *(const short8*)(&As[(wv * 16 + mr) * 40 + quad * 8]);
#pragma unroll
    for (int nt = 0; nt < 4; ++nt) {
      short8 bf = *(const short8*)(&Bs[(nt * 16 + mr) * 40 + quad * 8]);
      acc[nt] = __builtin_amdgcn_mfma_f32_16x16x32_bf16(af, bf, acc[nt], 0, 0, 0);
    }
    __syncthreads();
  }
#pragma unroll
  for (int nt = 0; nt < 4; ++nt) {
#pragma unroll
    for (int r = 0; r < 4; ++r) {
      int m = m0 + wv * 16 + quad * 4 + r;
      int n = n0 + nt * 16 + mr;
      float v = acc[nt][r];
      if (bias) v += bias[boff + n];
      if (relu) v = fmaxf(v, 0.f);
      if (kvmode == 1) {
        int b = m >> 10, i = m & 1023, h = n >> 5, d = n & 31;
        cbf[(size_t)(((b << 3) + h) * 32 + d) * 1024 + i] = f2bf(v);
      } else if (kvmode == 2) {
        int b = m >> 10, i = m & 1023, h = n >> 5, d = n & 31;
        cbf[(size_t)(((b << 3) + h) * 1024 + i) * 32 + d] = f2bf(v);
      } else if (cbf) {
        cbf[(size_t)m * N + n] = f2bf(v);
      } else {
        C[(size_t)m * N + n] = v;
      }
    }
  }
}

__global__ __launch_bounds__(256) void mgemm_k(
    const void* __restrict__ A, int a_bf, const ushortt* __restrict__ BT,
    const float* __restrict__ bias, size_t boff,
    float* __restrict__ C, ushortt* __restrict__ cbf,
    int N, int K, int relu)
{
  mgemm_body(A, a_bf, BT, bias, boff, C, cbf,
             blockIdx.y * 64, blockIdx.x * 64, N, K, relu, 0);
}

// fused QKV: sel 0 -> q fp32; sel 1 (Wk) -> k bf16 [j][d]; sel 2 (Wv) -> v bf16 [d][j]
__global__ __launch_bounds__(256) void mqkv_k(
    const float* __restrict__ x, const ushortt* __restrict__ WT,
    float* __restrict__ q, ushortt* __restrict__ kbf, ushortt* __restrict__ vTbf)
{
  int sel = blockIdx.x >> 2;
  const ushortt* BT = WT + (size_t)sel * 65536;
  int mode = (sel == 1) ? 2 : (sel == 2) ? 1 : 0;
  mgemm_body(x, 0, BT, nullptr, 0,
             (sel == 0) ? q : nullptr,
             (sel == 1) ? kbf : (sel == 2) ? vTbf : nullptr,
             blockIdx.y * 64, (blockIdx.x & 3) * 64, 256, 256, 0, mode);
}

// ---------- MFMA attention: block = (b, h, 8 i's), ~24 KB LDS ----------
__global__ __launch_bounds__(256) void attn_mf8_k(
    const float* __restrict__ q, const ushortt* __restrict__ kbf,
    const ushortt* __restrict__ vTbf, const float* __restrict__ Ek,
    const float* __restrict__ Ev, const int* __restrict__ rel,
    const int* __restrict__ msk, float* __restrict__ out)
{
  __shared__ ushortt pbf[8 * 1028];    // 16.4 KB
  __shared__ float regA[1072];         // qs[8*33]+qek[8*101]; later pvpart[256]+pvtot[256]
  __shared__ float wbin[8 * 101];
  __shared__ float denom4[32];

  int tid = threadIdx.x;
  int wv = tid >> 6, lane = tid & 63;
  int quad = lane >> 4, mr = lane & 15;
  int tile = blockIdx.x & 127;
  int h = (blockIdx.x >> 7) & 7;
  int b = blockIdx.x >> 10;
  int i0 = tile << 3;

  float* qs = regA;            // [8][33]
  float* qek = regA + 264;     // [8][101]

  {
    int i = tid >> 5, d = tid & 31;    // 256 = 8*32 exact
    qs[i * 33 + d] = q[(((size_t)(b * 1024 + i0 + i) * 8 + h) << 5) + d]
                     * 0.17677669529663687f;
  }
  for (int p = tid; p < 808; p += 256) wbin[p] = 0.f;
  __syncthreads();  // (1)

  for (int p = tid; p < 800; p += 256) {
    int i = p / 100, r = p - i * 100;
    const float* ep = Ek + (r << 5);
    float s = 0.f;
#pragma unroll
    for (int d = 0; d < 32; ++d) s += qs[i * 33 + d] * ep[d];
    qek[i * 101 + r] = s;
  }
  __syncthreads();  // (2)

  // A-frag (q): A[m=mr][k=quad*8+jj]; rows 8..15 don't-care (read in-bounds garbage)
  short8 qf;
#pragma unroll
  for (int jj = 0; jj < 8; ++jj)
    ((ushortt*)&qf)[jj] = f2bf(qs[mr * 33 + quad * 8 + jj]);

  const ushortt* ks = kbf + ((size_t)(b * 8 + h) << 15);   // [j][d]
  const ushortt* vs = vTbf + ((size_t)(b * 8 + h) << 15);  // [d][j]

  // ---- scores: wave wv covers j-quarter, 16 tiles; only quads 0,1 epilogue ----
  float psum[4] = {0.f, 0.f, 0.f, 0.f};
  for (int t = 0; t < 16; ++t) {
    int j0 = (wv * 16 + t) << 4;
    short8 kf = *(const short8*)(ks + ((size_t)(j0 + mr) << 5) + quad * 8);
    f32x4 z = {};
    f32x4 s = __builtin_amdgcn_mfma_f32_16x16x32_bf16(qf, kf, z, 0, 0, 0);
    if (quad < 2) {
#pragma unroll
      for (int r = 0; r < 4; ++r) {
        int i = quad * 4 + r;          // 0..7
        int j = j0 + mr;
        size_t ro = ((size_t)(b * 1024 + i0 + i) << 10) + j;
        int rv = rel[ro];
        float p = 0.f;
        if (!msk[ro]) {
          p = __expf(s[r] + qek[i * 101 + rv]);
          atomicAdd(&wbin[i * 101 + rv], p);
        }
        psum[r] += p;
        pbf[i * 1028 + j] = f2bf(p);
      }
    }
  }
#pragma unroll
  for (int r = 0; r < 4; ++r) {
    float s = psum[r];
    s += __shfl_xor(s, 1, 64);
    s += __shfl_xor(s, 2, 64);
    s += __shfl_xor(s, 4, 64);
    s += __shfl_xor(s, 8, 64);
    if (mr == 0 && quad < 2) denom4[wv * 8 + quad * 4 + r] = s;
  }
  __syncthreads();  // (3) pbf, wbin, denom complete; regA free

  // ---- PV: ntile = wv&1 (d0), khalf = wv>>1 (k0); A rows 8..15 alias 0..7 ----
  float* pvpart = regA;        // [2][8][16]
  float* pvtot  = regA + 256;  // [8][32]
  int d0 = (wv & 1) << 4;
  int k0 = (wv >> 1) << 9;
  int prow = (mr & 7) * 1028;
  f32x4 acc = {};
  for (int kt = 0; kt < 16; ++kt) {
    int kk = k0 + (kt << 5);
    short8 pf = *(const short8*)(&pbf[prow + kk + quad * 8]);
    short8 vf = *(const short8*)(vs + ((size_t)(d0 + mr) << 10) + kk + quad * 8);
    acc = __builtin_amdgcn_mfma_f32_16x16x32_bf16(pf, vf, acc, 0, 0, 0);
  }
  if (wv >= 2 && quad < 2) {
#pragma unroll
    for (int r = 0; r < 4; ++r)
      pvpart[((wv & 1) << 7) + (quad * 4 + r) * 16 + mr] = acc[r];
  }
  __syncthreads();  // (4)
  if (wv < 2 && quad < 2) {
#pragma unroll
    for (int r = 0; r < 4; ++r) {
      int i = quad * 4 + r;
      pvtot[i * 32 + d0 + mr] = acc[r] + pvpart[((wv & 1) << 7) + i * 16 + mr];
    }
  }
  __syncthreads();  // (5)

  // ---- final: all 256 threads, i = tid>>5, d = tid&31 ----
  {
    int i = tid >> 5, d = tid & 31;
    float ev = 0.f;
    for (int rr = 0; rr < 100; ++rr)
      ev += wbin[i * 101 + rr] * Ev[(rr << 5) + d];
    float den = denom4[i] + denom4[8 + i] + denom4[16 + i] + denom4[24 + i];
    out[(((size_t)(b * 1024 + i0 + i) * 8 + h) << 5) + d] =
        (pvtot[i * 32 + d] + ev) / den;
  }
}

// ---------- residual + LayerNorm ----------
__global__ __launch_bounds__(256) void ln_k(
    const float* __restrict__ x, const float* __restrict__ o,
    const float* __restrict__ g, const float* __restrict__ bta, size_t eoff,
    float* __restrict__ xo, float* __restrict__ fout)
{
  __shared__ float red[256];
  int row = blockIdx.x, t = threadIdx.x;
  size_t idx = (size_t)row * 256 + t;
  float r = x[idx] + o[idx];
  red[t] = r;
  __syncthreads();
  for (int off = 128; off > 0; off >>= 1) {
    if (t < off) red[t] += red[t + off];
    __syncthreads();
  }
  float mean = red[0] * (1.f / 256.f);
  __syncthreads();
  float dv = r - mean;
  red[t] = dv * dv;
  __syncthreads();
  for (int off = 128; off > 0; off >>= 1) {
    if (t < off) red[t] += red[t + off];
    __syncthreads();
  }
  float var = red[0] * (1.f / 256.f);
  float val = dv * rsqrtf(var + 1e-5f) * g[eoff + t] + bta[eoff + t];
  xo[idx] = val;
  if (fout) fout[idx] = val;
}

extern "C" void kernel_launch(void* const* d_in, const int* in_sizes, int n_in,
                              void* d_out, int out_size, void* d_ws, size_t ws_size,
                              hipStream_t stream) {
  const float* inp  = (const float*)d_in[0];
  const float* Wq   = (const float*)d_in[1];
  const float* Wk   = (const float*)d_in[2];
  const float* Wv   = (const float*)d_in[3];
  const float* Wo   = (const float*)d_in[4];
  const float* bo   = (const float*)d_in[5];
  const float* W1   = (const float*)d_in[6];
  const float* b1   = (const float*)d_in[7];
  const float* W2   = (const float*)d_in[8];
  const float* b2   = (const float*)d_in[9];
  const float* ln1g = (const float*)d_in[10];
  const float* ln1b = (const float*)d_in[11];
  const float* ln2g = (const float*)d_in[12];
  const float* ln2b = (const float*)d_in[13];
  const float* Ek   = (const float*)d_in[14];
  const float* Ev   = (const float*)d_in[15];
  const int*   rel  = (const int*)d_in[16];
  const int*   msk  = (const int*)d_in[17];

  const size_t SZ = 524288;  // 2048*256
  float* x      = (float*)d_ws;              // 2 MB
  float* q      = x + SZ;                    // 2 MB fp32
  ushortt* kbf  = (ushortt*)(q + SZ);        // 1 MB bf16 [j][d]
  ushortt* vTbf = kbf + SZ;                  // 1 MB bf16 [d][j]
  float* attn   = (float*)(vTbf + SZ);       // 2 MB
  float* tmp    = attn + SZ;                 // 2 MB
  ushortt* wbuf = (ushortt*)(tmp + SZ);      // 3 MB (both layers)
  ushortt* ffh  = (ushortt*)q;               // 4 MB alias over q+kbf+vTbf

  dim3 blk(256);
  wcvt_all_k<<<3072, blk, 0, stream>>>(Wq, Wk, Wv, Wo, W1, W2, wbuf);

  for (int l = 0; l < 2; ++l) {
    size_t o_b  = (size_t)l * 256;
    size_t o_b1 = (size_t)l * 1024;
    const float* xin = (l == 0) ? inp : x;
    ushortt* wl = wbuf + (size_t)l * 786432;

    mqkv_k<<<dim3(12, 32), blk, 0, stream>>>(xin, wl, q, kbf, vTbf);

    attn_mf8_k<<<2048, blk, 0, stream>>>(q, kbf, vTbf, Ek, Ev, rel, msk, attn);

    mgemm_k<<<dim3(4, 32), blk, 0, stream>>>(attn, 0, wl + 196608,
                                             bo, o_b, tmp, nullptr, 256, 256, 0);
    ln_k<<<2048, blk, 0, stream>>>(xin, tmp, ln1g, ln1b, o_b, x, nullptr);

    mgemm_k<<<dim3(16, 32), blk, 0, stream>>>(x, 0, wl + 262144,
                                              b1, o_b1, nullptr, ffh, 1024, 256, 1);
    mgemm_k<<<dim3(4, 32), blk, 0, stream>>>(ffh, 1, wl + 524288,
                                             b2, o_b, tmp, nullptr, 256, 1024, 0);
    ln_k<<<2048, blk, 0, stream>>>(x, tmp, ln2g, ln2b, o_b, x,
                                   (l == 1) ? (float*)d_out : nullptr);
  }
}